// Round 11
// baseline (113.639 us; speedup 1.0000x reference)
//
#include <hip/hip_runtime.h>

#define PIMG 1024   // H*W = 32*32
#define CCH  128    // channels
#define KG   68     // clusters incl. ghost
#define KR   64     // real clusters
#define T1   64     // pixels per block (kernel 1)

typedef float f4v __attribute__((ext_vector_type(4)));

// ---------------- Kernel 1: norms + logits + softmax (v3b) ----------------
// grid: N*16 = 128 blocks, 256 threads (4 waves). Lane = pixel; x column in
// 128 VGPRs (full unroll -> static indexing); norm per-lane; k wave-uniform
// (readfirstlane) so conv_w flows via s_load/SGPR -> logit loop is pure
// v_fmac(v,s,v). Numerics: 4-way partial sums + normalize-before-dot
// (matches reference order; v3's single 128-chains tripped the threshold).
__global__ __launch_bounds__(256) void nv_assign_kernel(
    const float* __restrict__ x,       // [N,128,1024]
    const float* __restrict__ conv_w,  // [68,128]
    float* __restrict__ sa_out,        // [N,68,1024]
    float* __restrict__ rnorm_ws)      // [N*1024]
{
    __shared__ float lg[KG][T1 + 2];  // logits -> exp, pitch 66 (17.9 KB)
    __shared__ float red[4][T1];
    __shared__ float mx_l[T1];
    __shared__ float is_l[T1];

    const int t    = threadIdx.x;
    const int lane = t & 63;
    const int wv   = __builtin_amdgcn_readfirstlane(t >> 6);  // 0..3, uniform
    const int gp0  = blockIdx.x * T1;
    const int n    = gp0 >> 10;
    const int p0   = gp0 & 1023;

    // x column for this lane's pixel -> registers (L1/L2-resident, 4 MB total)
    const float* xp = x + (size_t)n * (CCH * PIMG) + p0 + lane;
    float xr[CCH];
    #pragma unroll
    for (int c = 0; c < CCH; ++c) xr[c] = xp[c * PIMG];

    // sum of squares with 4 partial chains (32 terms each)
    float s0 = 0.f, s1 = 0.f, s2 = 0.f, s3 = 0.f;
    #pragma unroll
    for (int c = 0; c < CCH; c += 4) {
        s0 += xr[c + 0] * xr[c + 0];
        s1 += xr[c + 1] * xr[c + 1];
        s2 += xr[c + 2] * xr[c + 2];
        s3 += xr[c + 3] * xr[c + 3];
    }
    const float rn = 1.0f / fmaxf(sqrtf((s0 + s1) + (s2 + s3)), 1e-12f);
    if (t < T1) rnorm_ws[gp0 + t] = rn;   // wave 0's lanes cover all pixels

    // normalize in-register (reference order: xn = x*rn, then dot with w)
    #pragma unroll
    for (int c = 0; c < CCH; ++c) xr[c] *= rn;

    // logits: wave wv handles k = wv, wv+4, ... (uniform -> s_load w row)
    #pragma unroll 2
    for (int k = wv; k < KG; k += 4) {
        const float* wr = conv_w + k * CCH;
        float a0 = 0.f, a1 = 0.f, a2 = 0.f, a3 = 0.f;
        #pragma unroll
        for (int c = 0; c < CCH; c += 4) {
            a0 += xr[c + 0] * wr[c + 0];
            a1 += xr[c + 1] * wr[c + 1];
            a2 += xr[c + 2] * wr[c + 2];
            a3 += xr[c + 3] * wr[c + 3];
        }
        lg[k][lane] = (a0 + a1) + (a2 + a3);
    }
    __syncthreads();

    // softmax over k: 4 threads per pixel (q = wv, conflict-free rows)
    {
        float m = -1e30f;
        for (int k = wv; k < KG; k += 4) m = fmaxf(m, lg[k][lane]);
        red[wv][lane] = m;
    }
    __syncthreads();
    if (t < T1)
        mx_l[t] = fmaxf(fmaxf(red[0][t], red[1][t]),
                        fmaxf(red[2][t], red[3][t]));
    __syncthreads();
    {
        float m = mx_l[lane], s = 0.f;
        for (int k = wv; k < KG; k += 4) {
            float e = expf(lg[k][lane] - m);
            lg[k][lane] = e;
            s += e;
        }
        red[wv][lane] = s;
    }
    __syncthreads();
    if (t < T1)
        is_l[t] = 1.0f / (red[0][t] + red[1][t] + red[2][t] + red[3][t]);
    __syncthreads();

    // write soft_assign (coalesced over pix)
    for (int i = t; i < KG * T1; i += 256) {
        int k = i >> 6, pix = i & 63;
        sa_out[((size_t)n * KG + k) * PIMG + p0 + pix] = lg[k][pix] * is_l[pix];
    }
}

// ---------------- Kernel 2: streaming residual write (R4 best) -------------
// grid: N*64*4 blocks, one per (n, k, c-quarter); 256 threads; thread owns 4
// pixels. Plain stores.
__global__ __launch_bounds__(256) void nv_resid_kernel(
    const float* __restrict__ x,          // [N,128,1024]
    const float* __restrict__ centroids,  // [68,128]
    const float* __restrict__ sa,         // [N,68,1024]
    const float* __restrict__ rnorm,      // [N,1024]
    float* __restrict__ out)              // [N,64,128,1024]
{
    const int b  = blockIdx.x;
    const int n  = b >> 8;
    const int k  = (b >> 2) & 63;
    const int c0 = (b & 3) << 5;
    const int t  = threadIdx.x;

    const f4v rn4 = ((const f4v*)(rnorm + (size_t)n * PIMG))[t];
    const f4v a4  = ((const f4v*)(sa + ((size_t)n * KG + k) * PIMG))[t];
    const f4v ra  = rn4 * a4;   // out = x*(rn*a) - cent*a

    const float* cw = centroids + k * CCH + c0;      // uniform -> s_load
    const float* xb = x + (size_t)n * (CCH * PIMG) + (size_t)c0 * PIMG;
    float* ob = out + (((size_t)n * KR + k) * CCH + c0) * PIMG;

    #pragma unroll 8
    for (int c = 0; c < 32; ++c) {
        f4v xv = ((const f4v*)(xb + c * PIMG))[t];
        float ce = cw[c];
        f4v o = xv * ra - ce * a4;
        ((f4v*)(ob + c * PIMG))[t] = o;
    }
}

extern "C" void kernel_launch(void* const* d_in, const int* in_sizes, int n_in,
                              void* d_out, int out_size, void* d_ws, size_t ws_size,
                              hipStream_t stream) {
    const float* x         = (const float*)d_in[0];
    const float* conv_w    = (const float*)d_in[1];
    const float* centroids = (const float*)d_in[2];

    const int N = in_sizes[0] / (CCH * PIMG);   // 8

    float* out    = (float*)d_out;
    float* sa_out = out + (size_t)N * KR * CCH * PIMG;  // second tuple element
    float* rnorm  = (float*)d_ws;                        // N*1024 floats

    nv_assign_kernel<<<N * (PIMG / T1), 256, 0, stream>>>(x, conv_w, sa_out, rnorm);
    nv_resid_kernel<<<N * KR * 4, 256, 0, stream>>>(x, centroids, sa_out, rnorm, out);
}

// Round 12
// 57.218 us; speedup vs baseline: 1.9861x; 1.9861x over previous
//
#include <hip/hip_runtime.h>

#define PIMG 1024   // H*W = 32*32
#define CCH  128    // channels
#define KG   68     // clusters incl. ghost
#define KR   64     // real clusters
#define T1   32     // pixels per block
#define XP   36     // xs pitch (mult of 4 for b128 align; bank-balanced)
#define WP   132    // wl pitch (v2 proven)
#define LP   36     // lg pitch

typedef float f4v __attribute__((ext_vector_type(4)));

// ---------------- Fused kernel: assign + residual, read-free store phase ----
// grid: N*32 = 256 blocks (32 pixels each), 512 threads (8 waves).
// Phases: stage(x,conv_w) -> norm -> normalize xs in place -> logits (v2
// structure) -> softmax -> finalize a in LDS + write sa -> pure store loop
// (LDS xn + LDS->L1 centroid + global_store only; NO global reads of x/sa).
__global__ __launch_bounds__(512) void nv_fused_kernel(
    const float* __restrict__ x,          // [N,128,1024]
    const float* __restrict__ conv_w,     // [68,128]
    const float* __restrict__ centroids,  // [68,128]
    float* __restrict__ out,              // [N,64,128,1024]
    float* __restrict__ sa_out)           // [N,68,1024]
{
    __shared__ float xs[CCH * XP];   // x tile -> xn tile [c][pix]  18.4 KB
    __shared__ float wl[KG * WP];    // padded conv_w               35.9 KB
    __shared__ float lg[KG * LP];    // logits -> exp -> a          9.8 KB
    __shared__ float red[16 * T1];   // reduction scratch           2 KB
    __shared__ float rn_l[T1];
    __shared__ float mx_l[T1];
    __shared__ float is_l[T1];

    const int t   = threadIdx.x;
    const int gp0 = blockIdx.x * T1;
    const int n   = gp0 >> 10;
    const int p0  = gp0 & 1023;

    // ---- stage conv_w into padded LDS (f4 chunks, coalesced) ----
    for (int i = t; i < KG * (CCH / 4); i += 512) {
        int k = i >> 5, c4 = i & 31;
        *(f4v*)(wl + k * WP + c4 * 4) = ((const f4v*)(conv_w + k * CCH))[c4];
    }
    // ---- stage x tile (b32, coalesced over pix) ----
    const float* xb = x + (size_t)n * (CCH * PIMG) + p0;
    for (int i = t; i < CCH * T1; i += 512) {
        int c = i >> 5, pix = i & 31;
        xs[c * XP + pix] = xb[c * PIMG + pix];
    }
    __syncthreads();

    // ---- norms: 16 threads per pixel, 8 channels each ----
    {
        int pix = t & 31, q = t >> 5;
        float s = 0.f;
        #pragma unroll
        for (int c = q * 8; c < q * 8 + 8; ++c) {
            float v = xs[c * XP + pix];
            s += v * v;
        }
        red[q * T1 + pix] = s;
    }
    __syncthreads();
    if (t < T1) {
        float s = 0.f;
        #pragma unroll
        for (int q = 0; q < 16; ++q) s += red[q * T1 + t];
        rn_l[t] = 1.0f / fmaxf(sqrtf(s), 1e-12f);
    }
    __syncthreads();
    // ---- normalize xs in place (xn = x * rn, reference order) ----
    for (int i = t; i < CCH * T1; i += 512) {
        int pix = i & 31;
        xs[(i >> 5) * XP + pix] *= rn_l[pix];
    }
    __syncthreads();

    // ---- logits: task = (k, pix4); wave-uniform k octets (v2 structure) ----
    for (int task = t; task < KG * 8; task += 512) {
        int g = task & 7, k = task >> 3;
        const float* wr = wl + k * WP;
        const float* xr = xs + g * 4;
        f4v acc = {0.f, 0.f, 0.f, 0.f};
        #pragma unroll 8
        for (int c0 = 0; c0 < CCH; c0 += 4) {
            f4v w4 = *(const f4v*)(wr + c0);
            acc += *(const f4v*)(xr + (c0 + 0) * XP) * w4.x;
            acc += *(const f4v*)(xr + (c0 + 1) * XP) * w4.y;
            acc += *(const f4v*)(xr + (c0 + 2) * XP) * w4.z;
            acc += *(const f4v*)(xr + (c0 + 3) * XP) * w4.w;
        }
        float* lr = lg + k * LP + g * 4;
        lr[0] = acc.x; lr[1] = acc.y; lr[2] = acc.z; lr[3] = acc.w;
    }
    __syncthreads();

    // ---- softmax over k: 16 threads per pixel ----
    {
        int pix = t & 31, q = t >> 5;
        float m = -1e30f;
        for (int k = q; k < KG; k += 16) m = fmaxf(m, lg[k * LP + pix]);
        red[q * T1 + pix] = m;
    }
    __syncthreads();
    if (t < T1) {
        float m = red[t];
        #pragma unroll
        for (int q = 1; q < 16; ++q) m = fmaxf(m, red[q * T1 + t]);
        mx_l[t] = m;
    }
    __syncthreads();
    {
        int pix = t & 31, q = t >> 5;
        float m = mx_l[pix], s = 0.f;
        for (int k = q; k < KG; k += 16) {
            float e = expf(lg[k * LP + pix] - m);
            lg[k * LP + pix] = e;
            s += e;
        }
        red[q * T1 + pix] = s;
    }
    __syncthreads();
    if (t < T1) {
        float s = 0.f;
        #pragma unroll
        for (int q = 0; q < 16; ++q) s += red[q * T1 + t];
        is_l[t] = 1.0f / s;
    }
    __syncthreads();

    // ---- finalize a = e/sum in LDS + write soft_assign ----
    for (int i = t; i < KG * T1; i += 512) {
        int k = i >> 5, pix = i & 31;
        float v = lg[k * LP + pix] * is_l[pix];
        lg[k * LP + pix] = v;
        sa_out[((size_t)n * KG + k) * PIMG + p0 + pix] = v;
    }
    __syncthreads();

    // ---- pure store phase: NO global reads except L1-resident centroids ----
    // thread: g = pix4 group, kc0 = (k,c) seed; per wave k is uniform.
    {
        const int g = t & 7, kc0 = t >> 3;     // kc0: 0..63
        float* ob = out + (size_t)n * (KR * CCH * PIMG) + p0 + g * 4;
        #pragma unroll 4
        for (int r = 0; r < 128; ++r) {
            int kc = r * 64 + kc0;
            int k = kc >> 7, c = kc & 127;
            float ce = centroids[k * CCH + c];
            f4v xn4 = *(const f4v*)(xs + c * XP + g * 4);
            f4v a4  = *(const f4v*)(lg + k * LP + g * 4);
            f4v o = (xn4 - ce) * a4;
            *(f4v*)(ob + (size_t)kc * PIMG) = o;
        }
    }
}

extern "C" void kernel_launch(void* const* d_in, const int* in_sizes, int n_in,
                              void* d_out, int out_size, void* d_ws, size_t ws_size,
                              hipStream_t stream) {
    const float* x         = (const float*)d_in[0];
    const float* conv_w    = (const float*)d_in[1];
    const float* centroids = (const float*)d_in[2];

    const int N = in_sizes[0] / (CCH * PIMG);   // 8

    float* out    = (float*)d_out;
    float* sa_out = out + (size_t)N * KR * CCH * PIMG;  // second tuple element

    nv_fused_kernel<<<N * (PIMG / T1), 512, 0, stream>>>(
        x, conv_w, centroids, out, sa_out);
}

// Round 13
// 54.111 us; speedup vs baseline: 2.1001x; 1.0574x over previous
//
#include <hip/hip_runtime.h>

#define PIMG 1024   // H*W = 32*32
#define CCH  128    // channels
#define KG   68     // clusters incl. ghost
#define KR   64     // real clusters
#define T1   32     // pixels per block
#define XP   36     // xs pitch
#define WP   132    // wl pitch (row r starts at bank 4r%32; stride-17 quads -> conflict-free)
#define LP   36     // lg pitch

typedef float f4v __attribute__((ext_vector_type(4)));

// ---------------- Fused kernel v2: conflict-free store phase ----------------
// grid: N*32 = 256 blocks (32 pixels each), 512 threads (8 waves).
// Logits: 136 tasks (g, k-quad q), k = q+17j stride-17 -> wl reads hit 8
//   distinct bank-quads; xs reads broadcast (c uniform). 4x fewer xs bytes.
// Store: thread = (g, c-pair) holds xn in 2 f4 REGISTERS; k-loop wave-uniform
//   -> lg read is an 8-addr broadcast (conflict-free); no xs reads at all.
__global__ __launch_bounds__(512) void nv_fused_kernel(
    const float* __restrict__ x,          // [N,128,1024]
    const float* __restrict__ conv_w,     // [68,128]
    const float* __restrict__ centroids,  // [68,128]
    float* __restrict__ out,              // [N,64,128,1024]
    float* __restrict__ sa_out)           // [N,68,1024]
{
    __shared__ float xs[CCH * XP];   // x tile -> xn tile [c][pix]  18.4 KB
    __shared__ float wl[KG * WP];    // padded conv_w               35.9 KB
    __shared__ float lg[KG * LP];    // logits -> exp -> a          9.8 KB
    __shared__ float red[16 * T1];   // reduction scratch           2 KB
    __shared__ float rn_l[T1];
    __shared__ float mx_l[T1];
    __shared__ float is_l[T1];

    const int t   = threadIdx.x;
    const int gp0 = blockIdx.x * T1;
    const int n   = gp0 >> 10;
    const int p0  = gp0 & 1023;

    // ---- stage conv_w into padded LDS (f4 chunks, coalesced) ----
    for (int i = t; i < KG * (CCH / 4); i += 512) {
        int k = i >> 5, c4 = i & 31;
        *(f4v*)(wl + k * WP + c4 * 4) = ((const f4v*)(conv_w + k * CCH))[c4];
    }
    // ---- stage x tile (b32, coalesced over pix) ----
    const float* xb = x + (size_t)n * (CCH * PIMG) + p0;
    for (int i = t; i < CCH * T1; i += 512) {
        int c = i >> 5, pix = i & 31;
        xs[c * XP + pix] = xb[c * PIMG + pix];
    }
    __syncthreads();

    // ---- norms: 16 threads per pixel, 8 channels each ----
    {
        int pix = t & 31, q = t >> 5;
        float s = 0.f;
        #pragma unroll
        for (int c = q * 8; c < q * 8 + 8; ++c) {
            float v = xs[c * XP + pix];
            s += v * v;
        }
        red[q * T1 + pix] = s;
    }
    __syncthreads();
    if (t < T1) {
        float s = 0.f;
        #pragma unroll
        for (int q = 0; q < 16; ++q) s += red[q * T1 + t];
        rn_l[t] = 1.0f / fmaxf(sqrtf(s), 1e-12f);
    }
    __syncthreads();
    // ---- normalize xs in place (xn = x * rn, reference order) ----
    for (int i = t; i < CCH * T1; i += 512) {
        int pix = i & 31;
        xs[(i >> 5) * XP + pix] *= rn_l[pix];
    }
    __syncthreads();

    // ---- logits: 136 tasks = (g = pix4, q = k-quad), k = q + 17j ----
    if (t < 136) {
        const int g = t & 7, q = t >> 3;     // q: 0..16
        const float* xr = xs + g * 4;
        const float* w0 = wl + q * WP;
        const float* w1 = wl + (q + 17) * WP;
        const float* w2 = wl + (q + 34) * WP;
        const float* w3 = wl + (q + 51) * WP;
        f4v a0 = {0,0,0,0}, a1 = {0,0,0,0}, a2 = {0,0,0,0}, a3 = {0,0,0,0};
        #pragma unroll 8
        for (int c0 = 0; c0 < CCH; c0 += 4) {
            f4v x0 = *(const f4v*)(xr + (c0 + 0) * XP);
            f4v x1 = *(const f4v*)(xr + (c0 + 1) * XP);
            f4v x2 = *(const f4v*)(xr + (c0 + 2) * XP);
            f4v x3 = *(const f4v*)(xr + (c0 + 3) * XP);
            f4v v0 = *(const f4v*)(w0 + c0);
            f4v v1 = *(const f4v*)(w1 + c0);
            f4v v2 = *(const f4v*)(w2 + c0);
            f4v v3 = *(const f4v*)(w3 + c0);
            a0 += x0 * v0.x; a0 += x1 * v0.y; a0 += x2 * v0.z; a0 += x3 * v0.w;
            a1 += x0 * v1.x; a1 += x1 * v1.y; a1 += x2 * v1.z; a1 += x3 * v1.w;
            a2 += x0 * v2.x; a2 += x1 * v2.y; a2 += x2 * v2.z; a2 += x3 * v2.w;
            a3 += x0 * v3.x; a3 += x1 * v3.y; a3 += x2 * v3.z; a3 += x3 * v3.w;
        }
        *(f4v*)(lg + q * LP + g * 4)        = a0;
        *(f4v*)(lg + (q + 17) * LP + g * 4) = a1;
        *(f4v*)(lg + (q + 34) * LP + g * 4) = a2;
        *(f4v*)(lg + (q + 51) * LP + g * 4) = a3;
    }
    __syncthreads();

    // ---- softmax over k: 16 threads per pixel ----
    {
        int pix = t & 31, q = t >> 5;
        float m = -1e30f;
        for (int k = q; k < KG; k += 16) m = fmaxf(m, lg[k * LP + pix]);
        red[q * T1 + pix] = m;
    }
    __syncthreads();
    if (t < T1) {
        float m = red[t];
        #pragma unroll
        for (int q = 1; q < 16; ++q) m = fmaxf(m, red[q * T1 + t]);
        mx_l[t] = m;
    }
    __syncthreads();
    {
        int pix = t & 31, q = t >> 5;
        float m = mx_l[pix], s = 0.f;
        for (int k = q; k < KG; k += 16) {
            float e = expf(lg[k * LP + pix] - m);
            lg[k * LP + pix] = e;
            s += e;
        }
        red[q * T1 + pix] = s;
    }
    __syncthreads();
    if (t < T1) {
        float s = 0.f;
        #pragma unroll
        for (int q = 0; q < 16; ++q) s += red[q * T1 + t];
        is_l[t] = 1.0f / s;
    }
    __syncthreads();

    // ---- finalize a = e/sum in LDS + write soft_assign ----
    for (int i = t; i < KG * T1; i += 512) {
        int k = i >> 5, pix = i & 31;
        float v = lg[k * LP + pix] * is_l[pix];
        lg[k * LP + pix] = v;
        sa_out[((size_t)n * KG + k) * PIMG + p0 + pix] = v;
    }
    __syncthreads();

    // ---- store phase: xn in registers, a via broadcast, pure write stream --
    {
        const int g  = t & 7;        // pix4 group
        const int cp = t >> 3;       // c-pair: c = 2cp, 2cp+1
        const int c0 = 2 * cp, c1 = 2 * cp + 1;
        const f4v xn0 = *(const f4v*)(xs + c0 * XP + g * 4);
        const f4v xn1 = *(const f4v*)(xs + c1 * XP + g * 4);
        const float* cb = centroids;
        float* ob = out + (size_t)n * (KR * CCH * PIMG) + p0 + g * 4;

        #pragma unroll 4
        for (int k = 0; k < KR; ++k) {
            f4v a4 = *(const f4v*)(lg + k * LP + g * 4);   // broadcast read
            float ce0 = cb[k * CCH + c0];
            float ce1 = cb[k * CCH + c1];
            *(f4v*)(ob + ((size_t)k * CCH + c0) * PIMG) = (xn0 - ce0) * a4;
            *(f4v*)(ob + ((size_t)k * CCH + c1) * PIMG) = (xn1 - ce1) * a4;
        }
    }
}

extern "C" void kernel_launch(void* const* d_in, const int* in_sizes, int n_in,
                              void* d_out, int out_size, void* d_ws, size_t ws_size,
                              hipStream_t stream) {
    const float* x         = (const float*)d_in[0];
    const float* conv_w    = (const float*)d_in[1];
    const float* centroids = (const float*)d_in[2];

    const int N = in_sizes[0] / (CCH * PIMG);   // 8

    float* out    = (float*)d_out;
    float* sa_out = out + (size_t)N * KR * CCH * PIMG;  // second tuple element

    nv_fused_kernel<<<N * (PIMG / T1), 512, 0, stream>>>(
        x, conv_w, centroids, out, sa_out);
}